// Round 4
// baseline (463.187 us; speedup 1.0000x reference)
//
#include <hip/hip_runtime.h>
#include <math.h>

#define N_NODES 50000
#define N_EDGES 800000
#define N_GRAPHS 64

__device__ __forceinline__ float elu1(float v){ return v > 0.f ? v : expm1f(v); }

// p += sum_c att_c * leaky(v_c + r_c)   (leaky(u) = max(u, 0.2u))
__device__ __forceinline__ float dot4(float4 v, float4 r, float4 a, float p){
    float u;
    u = v.x + r.x; p = fmaf(fmaxf(u, 0.2f*u), a.x, p);
    u = v.y + r.y; p = fmaf(fmaxf(u, 0.2f*u), a.y, p);
    u = v.z + r.z; p = fmaf(fmaxf(u, 0.2f*u), a.z, p);
    u = v.w + r.w; p = fmaf(fmaxf(u, 0.2f*u), a.w, p);
    return p;
}
__device__ __forceinline__ float4 fma4(float e, float4 v, float4 a){
    a.x = fmaf(e, v.x, a.x); a.y = fmaf(e, v.y, a.y);
    a.z = fmaf(e, v.z, a.z); a.w = fmaf(e, v.w, a.w);
    return a;
}

// ---- lin1: out = x @ [Wl|Wr]; x [N,64], W [64,256] each -> xl,xr [N,256]
// grid (782, 4): blockIdx.y = 128-col block of the 512 combined cols.
// 256 thr; thread = 8 rows x 4 cols. Also zeroes deg[] (runs first).
__global__ __launch_bounds__(256) void k_lin1(const float* __restrict__ x,
        const float* __restrict__ Wl, const float* __restrict__ Wr,
        float* __restrict__ xl, float* __restrict__ xr, int* __restrict__ deg){
    __shared__ float xs[64][64];
    int t = threadIdx.x;
    int gid = (blockIdx.x*4 + blockIdx.y)*256 + t;
    if (gid < N_NODES) deg[gid] = 0;
    int n0 = blockIdx.x*64;
    int cb = blockIdx.y;
    const float4* xg = (const float4*)x;
    #pragma unroll
    for (int i=0;i<4;i++){
        int idx = t + 256*i;            // f4 index; 16 f4 per row
        int row = idx >> 4;
        float4 v = make_float4(0.f,0.f,0.f,0.f);
        if (n0+row < N_NODES) v = xg[(size_t)(n0+row)*16 + (idx&15)];
        ((float4*)xs)[idx] = v;
    }
    __syncthreads();
    const float* W = (cb < 2) ? Wl : Wr;
    int wc = (cb&1)*128 + (t&31)*4;     // col within W [0,256)
    int r0 = (t>>5)*8;
    float4 acc[8];
    #pragma unroll
    for (int r=0;r<8;r++) acc[r]=make_float4(0.f,0.f,0.f,0.f);
    for (int k0=0;k0<64;k0+=4){
        float4 xv[8];
        #pragma unroll
        for (int r=0;r<8;r++) xv[r] = *(const float4*)&xs[r0+r][k0];
        #pragma unroll
        for (int kk=0;kk<4;kk++){
            float4 w = *(const float4*)&W[(size_t)(k0+kk)*256 + wc];
            #pragma unroll
            for (int r=0;r<8;r++){
                float xvv = (kk==0)?xv[r].x:(kk==1)?xv[r].y:(kk==2)?xv[r].z:xv[r].w;
                acc[r] = fma4(xvv, w, acc[r]);
            }
        }
    }
    float* o = (cb<2) ? xl : xr;
    #pragma unroll
    for (int r=0;r<8;r++){
        int row = n0 + r0 + r;
        if (row < N_NODES) *(float4*)&o[(size_t)row*256 + wc] = acc[r];
    }
}

// ---- lin2: out = h @ [Wl2|Wr2]; h [N,256], W [256,64] each -> xl2,xr2 [N,64]
// 256 thr; block = 64 rows x 128 cols; thread = 8 rows x 4 cols.
__global__ __launch_bounds__(256) void k_lin2(const float* __restrict__ h,
        const float* __restrict__ Wl, const float* __restrict__ Wr,
        float* __restrict__ xl, float* __restrict__ xr){
    __shared__ float hs[64][256];
    int t = threadIdx.x;
    int n0 = blockIdx.x*64;
    const float4* hg = (const float4*)h;
    #pragma unroll
    for (int i=0;i<16;i++){
        int idx = t + 256*i;            // f4 idx; 64 f4 per row
        int row = idx >> 6;
        float4 v = make_float4(0.f,0.f,0.f,0.f);
        if (n0+row < N_NODES) v = hg[(size_t)(n0+row)*64 + (idx&63)];
        ((float4*)hs)[idx] = v;
    }
    __syncthreads();
    const float* W = ((t&31) < 16) ? Wl : Wr;
    int wc = ((t&31)&15)*4;             // col within W [0,64)
    int r0 = (t>>5)*8;
    float4 acc[8];
    #pragma unroll
    for (int r=0;r<8;r++) acc[r]=make_float4(0.f,0.f,0.f,0.f);
    for (int k0=0;k0<256;k0+=4){
        float4 xv[8];
        #pragma unroll
        for (int r=0;r<8;r++) xv[r] = *(const float4*)&hs[r0+r][k0];
        #pragma unroll
        for (int kk=0;kk<4;kk++){
            float4 w = *(const float4*)&W[(size_t)(k0+kk)*64 + wc];
            #pragma unroll
            for (int r=0;r<8;r++){
                float xvv = (kk==0)?xv[r].x:(kk==1)?xv[r].y:(kk==2)?xv[r].z:xv[r].w;
                acc[r] = fma4(xvv, w, acc[r]);
            }
        }
    }
    float* o = ((t&31)<16) ? xl : xr;
    #pragma unroll
    for (int r=0;r<8;r++){
        int row = n0 + r0 + r;
        if (row < N_NODES) *(float4*)&o[(size_t)row*64 + wc] = acc[r];
    }
}

// ---- CSR build over dst
__global__ void k_hist(const int* __restrict__ ei, int* __restrict__ deg){
    int e4 = blockIdx.x*256 + threadIdx.x;
    if (e4 < N_EDGES/4){
        int4 d = ((const int4*)(ei + N_EDGES))[e4];
        atomicAdd(&deg[d.x],1); atomicAdd(&deg[d.y],1);
        atomicAdd(&deg[d.z],1); atomicAdd(&deg[d.w],1);
    }
}

__global__ __launch_bounds__(1024) void k_scan_a(const int* __restrict__ deg,
        int* __restrict__ rowptr, int* __restrict__ partial){
    __shared__ int s[1024];
    int t = threadIdx.x; int i = blockIdx.x*1024 + t;
    int v = (i < N_NODES) ? deg[i] : 0;
    s[t] = v; __syncthreads();
    for (int off=1; off<1024; off<<=1){
        int add = (t>=off) ? s[t-off] : 0;
        __syncthreads();
        s[t] += add;
        __syncthreads();
    }
    if (i < N_NODES) rowptr[i] = s[t] - v;   // local exclusive
    if (t == 1023) partial[blockIdx.x] = s[1023];   // block total
}

__global__ __launch_bounds__(1024) void k_scan_c(int* __restrict__ rowptr,
        int* __restrict__ cursor, const int* __restrict__ partial){
    __shared__ int base;
    if (threadIdx.x == 0){
        int run = 0;
        for (int bk=0; bk<(int)blockIdx.x; bk++) run += partial[bk];
        base = run;
    }
    __syncthreads();
    int i = blockIdx.x*1024 + threadIdx.x;
    if (i < N_NODES){
        int r = rowptr[i] + base;
        rowptr[i] = r; cursor[i] = r;
    } else if (i == N_NODES){
        rowptr[N_NODES] = N_EDGES;
    }
}

__global__ void k_scatter(const int* __restrict__ ei, int* __restrict__ cursor,
                          int* __restrict__ srcs){
    int e4 = blockIdx.x*256 + threadIdx.x;
    if (e4 < N_EDGES/4){
        int4 sv = ((const int4*)ei)[e4];
        int4 dv = ((const int4*)(ei + N_EDGES))[e4];
        int p0 = atomicAdd(&cursor[dv.x],1); srcs[p0] = sv.x;
        int p1 = atomicAdd(&cursor[dv.y],1); srcs[p1] = sv.y;
        int p2 = atomicAdd(&cursor[dv.z],1); srcs[p2] = sv.z;
        int p3 = atomicAdd(&cursor[dv.w],1); srcs[p3] = sv.w;
    }
}

// ---- fused GAT layer 1: one wave per node (4/block).
// Lane layout: g = l>>4 (edge slot, 4 in flight), q = l&15 (16 channels: q*16..+15).
// Head h = q>>2; per-head dot reduce = 2 shfl steps within 4-lane cluster.
__global__ __launch_bounds__(256) void k_gat1(const float* __restrict__ xl,
        const float* __restrict__ xr, const int* __restrict__ srcs,
        const int* __restrict__ rowptr,
        const float* __restrict__ att, const float* __restrict__ b,
        float* __restrict__ h1){
    int w = threadIdx.x >> 6, l = threadIdx.x & 63;
    int n = blockIdx.x*4 + w;
    int g = l >> 4, q = l & 15;
    const float4* xl4 = (const float4*)xl;
    const float4* xrp = (const float4*)(xr + (size_t)n*256) + q*4;
    float4 r0 = xrp[0], r1 = xrp[1], r2 = xrp[2], r3 = xrp[3];
    const float4* ap = (const float4*)att + q*4;
    float4 t0 = ap[0], t1 = ap[1], t2 = ap[2], t3 = ap[3];
    float4 a0 = make_float4(0.f,0.f,0.f,0.f), a1 = a0, a2 = a0, a3 = a0;
    float dacc = 0.f;
    int beg = rowptr[n], end = rowptr[n+1];
    int nit = (end - beg + 3) >> 2;
    int j = beg + g;
    int s = (j < end) ? srcs[j] : 0;
    for (int it=0; it<nit; ++it){
        bool act = j < end;
        int jn = j + 4;
        int sn = (jn < end) ? srcs[jn] : 0;   // prefetch next slot's src
        const float4* xp = xl4 + (((size_t)(unsigned)s)<<6) + q*4;
        float4 v0 = xp[0], v1 = xp[1], v2 = xp[2], v3 = xp[3];
        float p = dot4(v0, r0, t0, 0.f);
        p = dot4(v1, r1, t1, p);
        p = dot4(v2, r2, t2, p);
        p = dot4(v3, r3, t3, p);
        p += __shfl_xor(p, 1);
        p += __shfl_xor(p, 2);
        float ex = act ? __expf(p) : 0.f;
        a0 = fma4(ex, v0, a0); a1 = fma4(ex, v1, a1);
        a2 = fma4(ex, v2, a2); a3 = fma4(ex, v3, a3);
        dacc += ex;
        s = sn; j = jn;
    }
    // combine the 4 edge-slot groups (lane bits 4,5)
    #pragma unroll
    for (int off=16; off<64; off<<=1){
        a0.x += __shfl_xor(a0.x, off); a0.y += __shfl_xor(a0.y, off);
        a0.z += __shfl_xor(a0.z, off); a0.w += __shfl_xor(a0.w, off);
        a1.x += __shfl_xor(a1.x, off); a1.y += __shfl_xor(a1.y, off);
        a1.z += __shfl_xor(a1.z, off); a1.w += __shfl_xor(a1.w, off);
        a2.x += __shfl_xor(a2.x, off); a2.y += __shfl_xor(a2.y, off);
        a2.z += __shfl_xor(a2.z, off); a2.w += __shfl_xor(a2.w, off);
        a3.x += __shfl_xor(a3.x, off); a3.y += __shfl_xor(a3.y, off);
        a3.z += __shfl_xor(a3.z, off); a3.w += __shfl_xor(a3.w, off);
        dacc  += __shfl_xor(dacc,  off);
    }
    if (g == 0){
        float inv = 1.f / (dacc + 1e-16f);
        const float4* bp = (const float4*)b + q*4;
        float4 b0 = bp[0], b1 = bp[1], b2 = bp[2], b3 = bp[3];
        float4 o0, o1, o2, o3;
        o0.x = elu1(fmaf(a0.x, inv, b0.x)); o0.y = elu1(fmaf(a0.y, inv, b0.y));
        o0.z = elu1(fmaf(a0.z, inv, b0.z)); o0.w = elu1(fmaf(a0.w, inv, b0.w));
        o1.x = elu1(fmaf(a1.x, inv, b1.x)); o1.y = elu1(fmaf(a1.y, inv, b1.y));
        o1.z = elu1(fmaf(a1.z, inv, b1.z)); o1.w = elu1(fmaf(a1.w, inv, b1.w));
        o2.x = elu1(fmaf(a2.x, inv, b2.x)); o2.y = elu1(fmaf(a2.y, inv, b2.y));
        o2.z = elu1(fmaf(a2.z, inv, b2.z)); o2.w = elu1(fmaf(a2.w, inv, b2.w));
        o3.x = elu1(fmaf(a3.x, inv, b3.x)); o3.y = elu1(fmaf(a3.y, inv, b3.y));
        o3.z = elu1(fmaf(a3.z, inv, b3.z)); o3.w = elu1(fmaf(a3.w, inv, b3.w));
        float4* op = (float4*)(h1 + (size_t)n*256) + q*4;
        op[0]=o0; op[1]=o1; op[2]=o2; op[3]=o3;
    }
}

// ---- fused GAT layer 2: one wave per node; g = l>>2 (16 edge slots),
// q = l&3 (16 channels each). Dot reduce = 2 shfl steps within 4-lane cluster.
__global__ __launch_bounds__(256) void k_gat2(const float* __restrict__ xl,
        const float* __restrict__ xr, const int* __restrict__ srcs,
        const int* __restrict__ rowptr,
        const float* __restrict__ att, const float* __restrict__ b,
        float* __restrict__ h2){
    int w = threadIdx.x >> 6, l = threadIdx.x & 63;
    int n = blockIdx.x*4 + w;
    int g = l >> 2, q = l & 3;
    const float4* xl4 = (const float4*)xl;
    const float4* xrp = (const float4*)(xr + (size_t)n*64) + q*4;
    float4 r0 = xrp[0], r1 = xrp[1], r2 = xrp[2], r3 = xrp[3];
    const float4* ap = (const float4*)att + q*4;
    float4 t0 = ap[0], t1 = ap[1], t2 = ap[2], t3 = ap[3];
    float4 a0 = make_float4(0.f,0.f,0.f,0.f), a1 = a0, a2 = a0, a3 = a0;
    float dacc = 0.f;
    int beg = rowptr[n], end = rowptr[n+1];
    int nit = (end - beg + 15) >> 4;
    int j = beg + g;
    int s = (j < end) ? srcs[j] : 0;
    for (int it=0; it<nit; ++it){
        bool act = j < end;
        int jn = j + 16;
        int sn = (jn < end) ? srcs[jn] : 0;
        const float4* xp = xl4 + (((size_t)(unsigned)s)<<4) + q*4;
        float4 v0 = xp[0], v1 = xp[1], v2 = xp[2], v3 = xp[3];
        float p = dot4(v0, r0, t0, 0.f);
        p = dot4(v1, r1, t1, p);
        p = dot4(v2, r2, t2, p);
        p = dot4(v3, r3, t3, p);
        p += __shfl_xor(p, 1);
        p += __shfl_xor(p, 2);
        float ex = act ? __expf(p) : 0.f;
        a0 = fma4(ex, v0, a0); a1 = fma4(ex, v1, a1);
        a2 = fma4(ex, v2, a2); a3 = fma4(ex, v3, a3);
        dacc += ex;
        s = sn; j = jn;
    }
    // combine the 16 edge-slot groups (lane bits 2..5)
    #pragma unroll
    for (int off=4; off<64; off<<=1){
        a0.x += __shfl_xor(a0.x, off); a0.y += __shfl_xor(a0.y, off);
        a0.z += __shfl_xor(a0.z, off); a0.w += __shfl_xor(a0.w, off);
        a1.x += __shfl_xor(a1.x, off); a1.y += __shfl_xor(a1.y, off);
        a1.z += __shfl_xor(a1.z, off); a1.w += __shfl_xor(a1.w, off);
        a2.x += __shfl_xor(a2.x, off); a2.y += __shfl_xor(a2.y, off);
        a2.z += __shfl_xor(a2.z, off); a2.w += __shfl_xor(a2.w, off);
        a3.x += __shfl_xor(a3.x, off); a3.y += __shfl_xor(a3.y, off);
        a3.z += __shfl_xor(a3.z, off); a3.w += __shfl_xor(a3.w, off);
        dacc  += __shfl_xor(dacc,  off);
    }
    if (g == 0){
        float inv = 1.f / (dacc + 1e-16f);
        const float4* bp = (const float4*)b + q*4;
        float4 b0 = bp[0], b1 = bp[1], b2 = bp[2], b3 = bp[3];
        float4 o0, o1, o2, o3;
        o0.x = elu1(fmaf(a0.x, inv, b0.x)); o0.y = elu1(fmaf(a0.y, inv, b0.y));
        o0.z = elu1(fmaf(a0.z, inv, b0.z)); o0.w = elu1(fmaf(a0.w, inv, b0.w));
        o1.x = elu1(fmaf(a1.x, inv, b1.x)); o1.y = elu1(fmaf(a1.y, inv, b1.y));
        o1.z = elu1(fmaf(a1.z, inv, b1.z)); o1.w = elu1(fmaf(a1.w, inv, b1.w));
        o2.x = elu1(fmaf(a2.x, inv, b2.x)); o2.y = elu1(fmaf(a2.y, inv, b2.y));
        o2.z = elu1(fmaf(a2.z, inv, b2.z)); o2.w = elu1(fmaf(a2.w, inv, b2.w));
        o3.x = elu1(fmaf(a3.x, inv, b3.x)); o3.y = elu1(fmaf(a3.y, inv, b3.y));
        o3.z = elu1(fmaf(a3.z, inv, b3.z)); o3.w = elu1(fmaf(a3.w, inv, b3.w));
        float4* op = (float4*)(h2 + (size_t)n*64) + q*4;
        op[0]=o0; op[1]=o1; op[2]=o2; op[3]=o3;
    }
}

__device__ __forceinline__ int lower_bound_i(const int* a, int n, int key){
    int lo = 0, hi = n;
    while (lo < hi){ int mid = (lo+hi)>>1; if (a[mid] < key) lo = mid+1; else hi = mid; }
    return lo;
}

// ---- global mean pool + MLP head fused: one block per graph (batch sorted)
__global__ __launch_bounds__(256) void k_poolmlp(const float* __restrict__ h2,
        const int* __restrict__ batch,
        const float* __restrict__ W3, const float* __restrict__ b3,
        const float* __restrict__ W4, const float* __restrict__ b4,
        float* __restrict__ out){
    int g = blockIdx.x, t = threadIdx.x;
    int c = t & 63, q = t >> 6;
    int start = lower_bound_i(batch, N_NODES, g);
    int end   = lower_bound_i(batch, N_NODES, g+1);
    float s = 0.f;
    for (int i = start + q; i < end; i += 4) s += h2[(size_t)i*64 + c];
    __shared__ float red[256];
    __shared__ float ps[64], zs[64];
    red[t] = s; __syncthreads();
    if (q == 0){
        float tot = red[c] + red[64+c] + red[128+c] + red[192+c];
        ps[c] = tot / fmaxf((float)(end - start), 1.f);
    }
    __syncthreads();
    if (q == 0){
        float a = b3[c];
        for (int k=0;k<64;k++) a = fmaf(ps[k], W3[k*64+c], a);
        zs[c] = fmaxf(a, 0.f);
    }
    __syncthreads();
    if (t < 2){
        float o = b4[t];
        for (int k=0;k<64;k++) o = fmaf(zs[k], W4[k*2+t], o);
        out[g*2 + t] = o;
    }
}

extern "C" void kernel_launch(void* const* d_in, const int* in_sizes, int n_in,
                              void* d_out, int out_size, void* d_ws, size_t ws_size,
                              hipStream_t stream) {
    const float* x    = (const float*)d_in[0];
    const int*   ei   = (const int*)  d_in[1];   // [2, E] flat
    const int*   batch= (const int*)  d_in[2];
    const float* Wl1  = (const float*)d_in[3];
    const float* Wr1  = (const float*)d_in[4];
    const float* att1 = (const float*)d_in[5];
    const float* b1   = (const float*)d_in[6];
    const float* Wl2  = (const float*)d_in[7];
    const float* Wr2  = (const float*)d_in[8];
    const float* att2 = (const float*)d_in[9];
    const float* b2   = (const float*)d_in[10];
    const float* W3   = (const float*)d_in[11];
    const float* b3   = (const float*)d_in[12];
    const float* W4   = (const float*)d_in[13];
    const float* b4   = (const float*)d_in[14];
    float* out = (float*)d_out;

    // workspace layout
    float* xl1 = (float*)d_ws;                          // [N,256]
    float* xr1 = xl1 + (size_t)N_NODES*256;             // [N,256]
    float* h1  = xr1 + (size_t)N_NODES*256;             // [N,256]
    // layer-2 buffers overlay xl1 (dead after k_gat1)
    float* xl2 = xl1;                                   // [N,64]
    float* xr2 = xl2 + (size_t)N_NODES*64;              // [N,64]
    float* h2  = xr2 + (size_t)N_NODES*64;              // [N,64]
    int* rowptr  = (int*)(h1 + (size_t)N_NODES*256);    // [N+1]
    int* cursor  = rowptr + (N_NODES+1);                // [N]
    int* partial = cursor + N_NODES;                    // [64]
    int* srcs    = partial + 64;                        // [E]
    int* deg     = srcs + N_EDGES;                      // [N]

    k_lin1<<<dim3(782,4), 256, 0, stream>>>(x, Wl1, Wr1, xl1, xr1, deg);

    k_hist<<<782, 256, 0, stream>>>(ei, deg);
    const int SCAN_BLKS = (N_NODES + 1023) / 1024;      // 49
    k_scan_a<<<SCAN_BLKS, 1024, 0, stream>>>(deg, rowptr, partial);
    k_scan_c<<<SCAN_BLKS, 1024, 0, stream>>>(rowptr, cursor, partial);
    k_scatter<<<782, 256, 0, stream>>>(ei, cursor, srcs);

    k_gat1<<<N_NODES/4, 256, 0, stream>>>(xl1, xr1, srcs, rowptr, att1, b1, h1);
    k_lin2<<<782, 256, 0, stream>>>(h1, Wl2, Wr2, xl2, xr2);
    k_gat2<<<N_NODES/4, 256, 0, stream>>>(xl2, xr2, srcs, rowptr, att2, b2, h2);
    k_poolmlp<<<N_GRAPHS, 256, 0, stream>>>(h2, batch, W3, b3, W4, b4, out);
}

// Round 5
// 346.031 us; speedup vs baseline: 1.3386x; 1.3386x over previous
//
#include <hip/hip_runtime.h>
#include <hip/hip_fp16.h>
#include <math.h>

#define N_NODES 50000
#define N_EDGES 800000
#define N_GRAPHS 64

__device__ __forceinline__ float elu1(float v){ return v > 0.f ? v : expm1f(v); }
__device__ __forceinline__ float4 fma4(float e, float4 v, float4 a){
    a.x = fmaf(e, v.x, a.x); a.y = fmaf(e, v.y, a.y);
    a.z = fmaf(e, v.z, a.z); a.w = fmaf(e, v.w, a.w);
    return a;
}
__device__ __forceinline__ void cvt8(float4 q, float* v){
    const __half2* h = (const __half2*)&q;
    float2 f;
    f = __half22float2(h[0]); v[0]=f.x; v[1]=f.y;
    f = __half22float2(h[1]); v[2]=f.x; v[3]=f.y;
    f = __half22float2(h[2]); v[4]=f.x; v[5]=f.y;
    f = __half22float2(h[3]); v[6]=f.x; v[7]=f.y;
}
// sum_c att_c * leaky(v_c + r_c), leaky(u)=max(u,0.2u)
__device__ __forceinline__ float dot8(const float* v, float4 r0, float4 r1,
                                      float4 a0, float4 a1){
    float p, u;
    u = v[0]+r0.x; p = fmaxf(u,0.2f*u)*a0.x;
    u = v[1]+r0.y; p = fmaf(fmaxf(u,0.2f*u), a0.y, p);
    u = v[2]+r0.z; p = fmaf(fmaxf(u,0.2f*u), a0.z, p);
    u = v[3]+r0.w; p = fmaf(fmaxf(u,0.2f*u), a0.w, p);
    u = v[4]+r1.x; p = fmaf(fmaxf(u,0.2f*u), a1.x, p);
    u = v[5]+r1.y; p = fmaf(fmaxf(u,0.2f*u), a1.y, p);
    u = v[6]+r1.z; p = fmaf(fmaxf(u,0.2f*u), a1.z, p);
    u = v[7]+r1.w; p = fmaf(fmaxf(u,0.2f*u), a1.w, p);
    return p;
}

// ---- lin1: x [N,64] @ [Wl|Wr] [64,256] -> xlh (fp16) , xr (fp32)
// grid (782,4): blockIdx.y in {0,1}: Wl cols -> xlh; {2,3}: Wr -> xr. Zeroes deg.
__global__ __launch_bounds__(256) void k_lin1(const float* __restrict__ x,
        const float* __restrict__ Wl, const float* __restrict__ Wr,
        __half* __restrict__ xlh, float* __restrict__ xr, int* __restrict__ deg){
    __shared__ float xs[64][64];
    int t = threadIdx.x;
    int gid = (blockIdx.x*4 + blockIdx.y)*256 + t;
    if (gid < N_NODES) deg[gid] = 0;
    int n0 = blockIdx.x*64;
    int cb = blockIdx.y;
    const float4* xg = (const float4*)x;
    #pragma unroll
    for (int i=0;i<4;i++){
        int idx = t + 256*i;            // f4 index; 16 f4 per row
        int row = idx >> 4;
        float4 v = make_float4(0.f,0.f,0.f,0.f);
        if (n0+row < N_NODES) v = xg[(size_t)(n0+row)*16 + (idx&15)];
        ((float4*)xs)[idx] = v;
    }
    __syncthreads();
    const float* W = (cb < 2) ? Wl : Wr;
    int wc = (cb&1)*128 + (t&31)*4;     // col within [0,256)
    int r0 = (t>>5)*8;
    float4 acc[8];
    #pragma unroll
    for (int r=0;r<8;r++) acc[r]=make_float4(0.f,0.f,0.f,0.f);
    for (int k0=0;k0<64;k0+=4){
        float4 xv[8];
        #pragma unroll
        for (int r=0;r<8;r++) xv[r] = *(const float4*)&xs[r0+r][k0];
        #pragma unroll
        for (int kk=0;kk<4;kk++){
            float4 w = *(const float4*)&W[(size_t)(k0+kk)*256 + wc];
            #pragma unroll
            for (int r=0;r<8;r++){
                float xvv = (kk==0)?xv[r].x:(kk==1)?xv[r].y:(kk==2)?xv[r].z:xv[r].w;
                acc[r] = fma4(xvv, w, acc[r]);
            }
        }
    }
    if (cb < 2){
        #pragma unroll
        for (int r=0;r<8;r++){
            int row = n0 + r0 + r;
            if (row < N_NODES){
                __half2* hp = (__half2*)&xlh[(size_t)row*256 + wc];
                hp[0] = __floats2half2_rn(acc[r].x, acc[r].y);
                hp[1] = __floats2half2_rn(acc[r].z, acc[r].w);
            }
        }
    } else {
        #pragma unroll
        for (int r=0;r<8;r++){
            int row = n0 + r0 + r;
            if (row < N_NODES) *(float4*)&xr[(size_t)row*256 + wc] = acc[r];
        }
    }
}

// ---- lin2: h1 [N,256] @ [Wl2|Wr2] [256,64] -> xl2h (fp16), xr2 (fp32)
__global__ __launch_bounds__(256) void k_lin2(const float* __restrict__ h,
        const float* __restrict__ Wl, const float* __restrict__ Wr,
        __half* __restrict__ xlh, float* __restrict__ xr){
    __shared__ float hs[64][256];
    int t = threadIdx.x;
    int n0 = blockIdx.x*64;
    const float4* hg = (const float4*)h;
    #pragma unroll
    for (int i=0;i<16;i++){
        int idx = t + 256*i;            // f4 idx; 64 f4 per row
        int row = idx >> 6;
        float4 v = make_float4(0.f,0.f,0.f,0.f);
        if (n0+row < N_NODES) v = hg[(size_t)(n0+row)*64 + (idx&63)];
        ((float4*)hs)[idx] = v;
    }
    __syncthreads();
    bool isL = (t&31) < 16;
    const float* W = isL ? Wl : Wr;
    int wc = ((t&31)&15)*4;             // col within [0,64)
    int r0 = (t>>5)*8;
    float4 acc[8];
    #pragma unroll
    for (int r=0;r<8;r++) acc[r]=make_float4(0.f,0.f,0.f,0.f);
    for (int k0=0;k0<256;k0+=4){
        float4 xv[8];
        #pragma unroll
        for (int r=0;r<8;r++) xv[r] = *(const float4*)&hs[r0+r][k0];
        #pragma unroll
        for (int kk=0;kk<4;kk++){
            float4 w = *(const float4*)&W[(size_t)(k0+kk)*64 + wc];
            #pragma unroll
            for (int r=0;r<8;r++){
                float xvv = (kk==0)?xv[r].x:(kk==1)?xv[r].y:(kk==2)?xv[r].z:xv[r].w;
                acc[r] = fma4(xvv, w, acc[r]);
            }
        }
    }
    if (isL){
        #pragma unroll
        for (int r=0;r<8;r++){
            int row = n0 + r0 + r;
            if (row < N_NODES){
                __half2* hp = (__half2*)&xlh[(size_t)row*64 + wc];
                hp[0] = __floats2half2_rn(acc[r].x, acc[r].y);
                hp[1] = __floats2half2_rn(acc[r].z, acc[r].w);
            }
        }
    } else {
        #pragma unroll
        for (int r=0;r<8;r++){
            int row = n0 + r0 + r;
            if (row < N_NODES) *(float4*)&xr[(size_t)row*64 + wc] = acc[r];
        }
    }
}

// ---- CSR build over dst; also zeroes pooled (blocks 0..15)
__global__ void k_hist(const int* __restrict__ ei, int* __restrict__ deg,
                       float* __restrict__ pooled){
    int t = threadIdx.x;
    if (blockIdx.x < 16) pooled[blockIdx.x*256 + t] = 0.f;
    int e4 = blockIdx.x*256 + t;
    if (e4 < N_EDGES/4){
        int4 d = ((const int4*)(ei + N_EDGES))[e4];
        atomicAdd(&deg[d.x],1); atomicAdd(&deg[d.y],1);
        atomicAdd(&deg[d.z],1); atomicAdd(&deg[d.w],1);
    }
}

__global__ __launch_bounds__(1024) void k_scan_a(const int* __restrict__ deg,
        int* __restrict__ rowptr, int* __restrict__ partial){
    __shared__ int s[1024];
    int t = threadIdx.x; int i = blockIdx.x*1024 + t;
    int v = (i < N_NODES) ? deg[i] : 0;
    s[t] = v; __syncthreads();
    for (int off=1; off<1024; off<<=1){
        int add = (t>=off) ? s[t-off] : 0;
        __syncthreads();
        s[t] += add;
        __syncthreads();
    }
    if (i < N_NODES) rowptr[i] = s[t] - v;   // local exclusive
    if (t == 1023) partial[blockIdx.x] = s[1023];
}

__global__ __launch_bounds__(1024) void k_scan_c(int* __restrict__ rowptr,
        int* __restrict__ cursor, const int* __restrict__ partial){
    __shared__ int base;
    if (threadIdx.x == 0){
        int run = 0;
        for (int bk=0; bk<(int)blockIdx.x; bk++) run += partial[bk];
        base = run;
    }
    __syncthreads();
    int i = blockIdx.x*1024 + threadIdx.x;
    if (i < N_NODES){
        int r = rowptr[i] + base;
        rowptr[i] = r; cursor[i] = r;
    } else if (i == N_NODES){
        rowptr[N_NODES] = N_EDGES;
    }
}

__global__ void k_scatter(const int* __restrict__ ei, int* __restrict__ cursor,
                          int* __restrict__ srcs){
    int e4 = blockIdx.x*256 + threadIdx.x;
    if (e4 < N_EDGES/4){
        int4 sv = ((const int4*)ei)[e4];
        int4 dv = ((const int4*)(ei + N_EDGES))[e4];
        int p0 = atomicAdd(&cursor[dv.x],1); srcs[p0] = sv.x;
        int p1 = atomicAdd(&cursor[dv.y],1); srcs[p1] = sv.y;
        int p2 = atomicAdd(&cursor[dv.z],1); srcs[p2] = sv.z;
        int p3 = atomicAdd(&cursor[dv.w],1); srcs[p3] = sv.w;
    }
}

// ---- fused GAT layer 1 (fp16 gather): wave per node, 4 nodes/block.
// 32 lanes per edge x 8 fp16 ch (one dwordx4); slot g=l>>5 (2), 2x unroll
// -> 4 edges in flight. Head reduce = shfl 1,2,4 within 8-lane cluster.
__global__ __launch_bounds__(256) void k_gat1(const __half* __restrict__ xlh,
        const float* __restrict__ xr, const int* __restrict__ srcs,
        const int* __restrict__ rowptr,
        const float* __restrict__ att, const float* __restrict__ b,
        float* __restrict__ h1){
    int w = threadIdx.x >> 6, l = threadIdx.x & 63;
    int n = blockIdx.x*4 + w;
    int g = l >> 5, sub = l & 31;
    const float4* xh4 = (const float4*)xlh;       // 32 f4 per row
    const float4* xrp = (const float4*)(xr + (size_t)n*256) + sub*2;
    float4 r0 = xrp[0], r1 = xrp[1];
    const float4* ap = (const float4*)att + sub*2;
    float4 a0 = ap[0], a1 = ap[1];
    float acc[8];
    #pragma unroll
    for (int c=0;c<8;c++) acc[c]=0.f;
    float dacc = 0.f;
    int beg = rowptr[n], end = rowptr[n+1];
    for (int j = beg; j < end; j += 8){
        int j0 = j+g, j1 = j+2+g, j2 = j+4+g, j3 = j+6+g;
        bool c0 = j0<end, c1 = j1<end, c2 = j2<end, c3 = j3<end;
        int s0 = c0 ? srcs[j0] : 0;
        int s1 = c1 ? srcs[j1] : 0;
        int s2 = c2 ? srcs[j2] : 0;
        int s3 = c3 ? srcs[j3] : 0;
        float4 q0 = xh4[(size_t)(unsigned)s0*32 + sub];
        float4 q1 = xh4[(size_t)(unsigned)s1*32 + sub];
        float4 q2 = xh4[(size_t)(unsigned)s2*32 + sub];
        float4 q3 = xh4[(size_t)(unsigned)s3*32 + sub];
        float v0[8], v1[8], v2[8], v3[8];
        cvt8(q0,v0); cvt8(q1,v1); cvt8(q2,v2); cvt8(q3,v3);
        float p0 = dot8(v0,r0,r1,a0,a1);
        float p1 = dot8(v1,r0,r1,a0,a1);
        float p2 = dot8(v2,r0,r1,a0,a1);
        float p3 = dot8(v3,r0,r1,a0,a1);
        #pragma unroll
        for (int off=1; off<8; off<<=1){
            p0 += __shfl_xor(p0, off);
            p1 += __shfl_xor(p1, off);
            p2 += __shfl_xor(p2, off);
            p3 += __shfl_xor(p3, off);
        }
        float e0 = c0 ? __expf(p0) : 0.f;
        float e1 = c1 ? __expf(p1) : 0.f;
        float e2 = c2 ? __expf(p2) : 0.f;
        float e3 = c3 ? __expf(p3) : 0.f;
        #pragma unroll
        for (int c=0;c<8;c++)
            acc[c] = fmaf(e0,v0[c], fmaf(e1,v1[c], fmaf(e2,v2[c], fmaf(e3,v3[c], acc[c]))));
        dacc += e0 + e1 + e2 + e3;
    }
    // combine the 2 slot groups (lane bit 5)
    #pragma unroll
    for (int c=0;c<8;c++) acc[c] += __shfl_xor(acc[c], 32);
    dacc += __shfl_xor(dacc, 32);
    if (l < 32){
        float inv = 1.f / (dacc + 1e-16f);
        const float4* bp = (const float4*)b + l*2;
        float4 b0 = bp[0], b1 = bp[1];
        float4 o0, o1;
        o0.x = elu1(fmaf(acc[0], inv, b0.x));
        o0.y = elu1(fmaf(acc[1], inv, b0.y));
        o0.z = elu1(fmaf(acc[2], inv, b0.z));
        o0.w = elu1(fmaf(acc[3], inv, b0.w));
        o1.x = elu1(fmaf(acc[4], inv, b1.x));
        o1.y = elu1(fmaf(acc[5], inv, b1.y));
        o1.z = elu1(fmaf(acc[6], inv, b1.z));
        o1.w = elu1(fmaf(acc[7], inv, b1.w));
        float4* op = (float4*)(h1 + (size_t)n*256) + l*2;
        op[0] = o0; op[1] = o1;
    }
}

// ---- fused GAT layer 2 (fp16 gather): wave per node; 8 lanes/edge,
// 8 slots x 2 unroll = 16 edges in flight.
__global__ __launch_bounds__(256) void k_gat2(const __half* __restrict__ xlh,
        const float* __restrict__ xr, const int* __restrict__ srcs,
        const int* __restrict__ rowptr,
        const float* __restrict__ att, const float* __restrict__ b,
        float* __restrict__ h2){
    int w = threadIdx.x >> 6, l = threadIdx.x & 63;
    int n = blockIdx.x*4 + w;
    int g = l >> 3, sub = l & 7;
    const float4* xh4 = (const float4*)xlh;       // 8 f4 per row
    const float4* xrp = (const float4*)(xr + (size_t)n*64) + sub*2;
    float4 r0 = xrp[0], r1 = xrp[1];
    const float4* ap = (const float4*)att + sub*2;
    float4 a0 = ap[0], a1 = ap[1];
    float acc[8];
    #pragma unroll
    for (int c=0;c<8;c++) acc[c]=0.f;
    float dacc = 0.f;
    int beg = rowptr[n], end = rowptr[n+1];
    for (int j = beg; j < end; j += 16){
        int j0 = j+g, j1 = j+8+g;
        bool c0 = j0<end, c1 = j1<end;
        int s0 = c0 ? srcs[j0] : 0;
        int s1 = c1 ? srcs[j1] : 0;
        float4 q0 = xh4[(size_t)(unsigned)s0*8 + sub];
        float4 q1 = xh4[(size_t)(unsigned)s1*8 + sub];
        float v0[8], v1[8];
        cvt8(q0,v0); cvt8(q1,v1);
        float p0 = dot8(v0,r0,r1,a0,a1);
        float p1 = dot8(v1,r0,r1,a0,a1);
        #pragma unroll
        for (int off=1; off<8; off<<=1){
            p0 += __shfl_xor(p0, off);
            p1 += __shfl_xor(p1, off);
        }
        float e0 = c0 ? __expf(p0) : 0.f;
        float e1 = c1 ? __expf(p1) : 0.f;
        #pragma unroll
        for (int c=0;c<8;c++)
            acc[c] = fmaf(e0,v0[c], fmaf(e1,v1[c], acc[c]));
        dacc += e0 + e1;
    }
    // combine the 8 slot groups (lane bits 3,4,5)
    #pragma unroll
    for (int off=8; off<64; off<<=1){
        #pragma unroll
        for (int c=0;c<8;c++) acc[c] += __shfl_xor(acc[c], off);
        dacc += __shfl_xor(dacc, off);
    }
    if (l < 8){
        float inv = 1.f / (dacc + 1e-16f);
        const float4* bp = (const float4*)b + l*2;
        float4 b0 = bp[0], b1 = bp[1];
        float4 o0, o1;
        o0.x = elu1(fmaf(acc[0], inv, b0.x));
        o0.y = elu1(fmaf(acc[1], inv, b0.y));
        o0.z = elu1(fmaf(acc[2], inv, b0.z));
        o0.w = elu1(fmaf(acc[3], inv, b0.w));
        o1.x = elu1(fmaf(acc[4], inv, b1.x));
        o1.y = elu1(fmaf(acc[5], inv, b1.y));
        o1.z = elu1(fmaf(acc[6], inv, b1.z));
        o1.w = elu1(fmaf(acc[7], inv, b1.w));
        float4* op = (float4*)(h2 + (size_t)n*64) + l*2;
        op[0] = o0; op[1] = o1;
    }
}

__device__ __forceinline__ int lower_bound_i(const int* a, int n, int key){
    int lo = 0, hi = n;
    while (lo < hi){ int mid = (lo+hi)>>1; if (a[mid] < key) lo = mid+1; else hi = mid; }
    return lo;
}

// ---- mean pool, parallel: grid (64 graphs, 8 parts); atomic into pooled
__global__ __launch_bounds__(256) void k_pool(const float* __restrict__ h2,
        const int* __restrict__ batch, float* __restrict__ pooled){
    int gph = blockIdx.x, part = blockIdx.y;
    int t = threadIdx.x, c = t & 63, q = t >> 6;
    int start = lower_bound_i(batch, N_NODES, gph);
    int end   = lower_bound_i(batch, N_NODES, gph+1);
    int len = end - start;
    int is = start + (int)(((long long)len*part) >> 3);
    int ie = start + (int)(((long long)len*(part+1)) >> 3);
    float s = 0.f;
    for (int i = is + q; i < ie; i += 4) s += h2[(size_t)i*64 + c];
    __shared__ float red[256];
    red[t] = s; __syncthreads();
    if (q == 0){
        float tot = red[c] + red[64+c] + red[128+c] + red[192+c];
        if (tot != 0.f || part == 0) atomicAdd(&pooled[gph*64 + c], tot);
    }
}

// ---- MLP head: one block per graph
__global__ __launch_bounds__(64) void k_mlp(const float* __restrict__ pooled,
        const int* __restrict__ batch,
        const float* __restrict__ W3, const float* __restrict__ b3,
        const float* __restrict__ W4, const float* __restrict__ b4,
        float* __restrict__ out){
    int gph = blockIdx.x, t = threadIdx.x;
    __shared__ float ps[64], zs[64];
    int start = lower_bound_i(batch, N_NODES, gph);
    int end   = lower_bound_i(batch, N_NODES, gph+1);
    float cnt = fmaxf((float)(end - start), 1.f);
    ps[t] = pooled[gph*64 + t] / cnt;
    __syncthreads();
    float a = b3[t];
    for (int k=0;k<64;k++) a = fmaf(ps[k], W3[k*64+t], a);
    zs[t] = fmaxf(a, 0.f); __syncthreads();
    if (t < 2){
        float o = b4[t];
        for (int k=0;k<64;k++) o = fmaf(zs[k], W4[k*2+t], o);
        out[gph*2 + t] = o;
    }
}

extern "C" void kernel_launch(void* const* d_in, const int* in_sizes, int n_in,
                              void* d_out, int out_size, void* d_ws, size_t ws_size,
                              hipStream_t stream) {
    const float* x    = (const float*)d_in[0];
    const int*   ei   = (const int*)  d_in[1];   // [2, E] flat
    const int*   batch= (const int*)  d_in[2];
    const float* Wl1  = (const float*)d_in[3];
    const float* Wr1  = (const float*)d_in[4];
    const float* att1 = (const float*)d_in[5];
    const float* b1   = (const float*)d_in[6];
    const float* Wl2  = (const float*)d_in[7];
    const float* Wr2  = (const float*)d_in[8];
    const float* att2 = (const float*)d_in[9];
    const float* b2   = (const float*)d_in[10];
    const float* W3   = (const float*)d_in[11];
    const float* b3   = (const float*)d_in[12];
    const float* W4   = (const float*)d_in[13];
    const float* b4   = (const float*)d_in[14];
    float* out = (float*)d_out;

    // workspace layout (overlays: region A reused by layer-2 tables,
    // region B (xr1) reused by h2+pooled after gat1)
    char* wsp = (char*)d_ws;
    const size_t A_BYTES = (size_t)N_NODES*256*sizeof(__half);   // 25.6 MB
    __half* xl1h = (__half*)wsp;                                 // [N,256] fp16
    __half* xl2h = (__half*)wsp;                                 // [N,64] fp16 (overlay)
    float*  xr2  = (float*)(wsp + (size_t)N_NODES*64*sizeof(__half)); // [N,64] f32 (overlay)
    float*  xr1  = (float*)(wsp + A_BYTES);                      // [N,256] f32
    float*  h2   = xr1;                                          // [N,64] (overlay)
    float*  pooled = h2 + (size_t)N_NODES*64;                    // [64,64]
    float*  h1   = (float*)(wsp + A_BYTES + (size_t)N_NODES*256*sizeof(float));
    int* rowptr  = (int*)(h1 + (size_t)N_NODES*256);             // [N+1]
    int* cursor  = rowptr + (N_NODES+1);                         // [N]
    int* partial = cursor + N_NODES;                             // [64]
    int* srcs    = partial + 64;                                 // [E]
    int* deg     = srcs + N_EDGES;                               // [N]

    k_lin1<<<dim3(782,4), 256, 0, stream>>>(x, Wl1, Wr1, xl1h, xr1, deg);

    k_hist<<<782, 256, 0, stream>>>(ei, deg, pooled);
    const int SCAN_BLKS = (N_NODES + 1023) / 1024;      // 49
    k_scan_a<<<SCAN_BLKS, 1024, 0, stream>>>(deg, rowptr, partial);
    k_scan_c<<<SCAN_BLKS, 1024, 0, stream>>>(rowptr, cursor, partial);
    k_scatter<<<782, 256, 0, stream>>>(ei, cursor, srcs);

    k_gat1<<<N_NODES/4, 256, 0, stream>>>(xl1h, xr1, srcs, rowptr, att1, b1, h1);
    k_lin2<<<782, 256, 0, stream>>>(h1, Wl2, Wr2, xl2h, xr2);
    k_gat2<<<N_NODES/4, 256, 0, stream>>>(xl2h, xr2, srcs, rowptr, att2, b2, h2);
    k_pool<<<dim3(N_GRAPHS,8), 256, 0, stream>>>(h2, batch, pooled);
    k_mlp<<<N_GRAPHS, 64, 0, stream>>>(pooled, batch, W3, b3, W4, b4, out);
}

// Round 6
// 296.506 us; speedup vs baseline: 1.5621x; 1.1670x over previous
//
#include <hip/hip_runtime.h>
#include <hip/hip_fp16.h>
#include <math.h>

#define N_NODES 50000
#define N_EDGES 800000
#define N_GRAPHS 64

#if __has_builtin(__builtin_amdgcn_fdot2)
#define HAS_FDOT2 1
typedef _Float16 h2_t __attribute__((ext_vector_type(2)));
#else
#define HAS_FDOT2 0
#endif

typedef _Float16 f16x8 __attribute__((ext_vector_type(8)));
typedef float f32x4 __attribute__((ext_vector_type(4)));

__device__ __forceinline__ float elu1(float v){ return v > 0.f ? v : expm1f(v); }

__device__ __forceinline__ void cvt8f(float4 q, float* v){
    const __half2* h = (const __half2*)&q;
    float2 f;
    f = __half22float2(h[0]); v[0]=f.x; v[1]=f.y;
    f = __half22float2(h[1]); v[2]=f.x; v[3]=f.y;
    f = __half22float2(h[2]); v[4]=f.x; v[5]=f.y;
    f = __half22float2(h[3]); v[6]=f.x; v[7]=f.y;
}

// partial logit: sum over this thread's 8 channels of att_c * leaky(q_c + r_c)
// leaky(u) = max(u,0.2u) = 0.6*u + 0.4*|u|  (fp16 consts 0x38CD+0x3666 sum to exactly 1.0)
__device__ __forceinline__ float pkdot(float4 q, const __half2* r2, const __half2* a2){
#if HAS_FDOT2
    const __half2 C06 = __builtin_bit_cast(__half2, 0x38CD38CDu); // 0.60009765625 x2
    const __half2 C04 = __builtin_bit_cast(__half2, 0x36663666u); // 0.39990234375 x2
    const __half2* qh = (const __half2*)&q;
    float p = 0.f;
    #pragma unroll
    for (int i=0;i<4;i++){
        __half2 u = __hadd2(qh[i], r2[i]);
        unsigned ua = __builtin_bit_cast(unsigned, u) & 0x7FFF7FFFu;
        __half2 lk = __hfma2(C06, u, __hmul2(C04, __builtin_bit_cast(__half2, ua)));
        p = __builtin_amdgcn_fdot2(__builtin_bit_cast(h2_t, lk),
                                   __builtin_bit_cast(h2_t, a2[i]), p, false);
    }
    return p;
#else
    const __half2* qh = (const __half2*)&q;
    float p = 0.f;
    #pragma unroll
    for (int i=0;i<4;i++){
        float2 qf = __half22float2(qh[i]);
        float2 rf = __half22float2(r2[i]);
        float2 af = __half22float2(a2[i]);
        float u0 = qf.x + rf.x, u1 = qf.y + rf.y;
        p = fmaf(fmaxf(u0, 0.2f*u0), af.x, p);
        p = fmaf(fmaxf(u1, 0.2f*u1), af.y, p);
    }
    return p;
#endif
}

// ---- prep: blocks [0,3125): x f32->fp16 ; [3125,3381): weight cvt+transpose
// (+ pooled zero) ; [3381,4163): dst-degree histogram. deg zeroed by memset.
__global__ __launch_bounds__(256) void k_prep(const float* __restrict__ x,
        const float* __restrict__ Wl1, const float* __restrict__ Wr1,
        const float* __restrict__ Wl2, const float* __restrict__ Wr2,
        const int* __restrict__ ei,
        __half* __restrict__ xh, __half* __restrict__ Wt1, __half* __restrict__ Wt2,
        int* __restrict__ deg, float* __restrict__ pooled){
    int t = threadIdx.x, bk = blockIdx.x;
    if (bk < 3125){
        int idx = bk*256 + t;                  // float4 index, 800000 total
        float4 v = ((const float4*)x)[idx];
        __half2* dst = (__half2*)xh + (size_t)idx*2;
        dst[0] = __floats2half2_rn(v.x, v.y);
        dst[1] = __floats2half2_rn(v.z, v.w);
    } else if (bk < 3381){
        int elem = (bk-3125)*256 + t;          // 0..65535
        if (elem < 32768){
            int c = elem >> 6, k = elem & 63;  // Wt1[c][k], c in [0,512)
            float v = (c < 256) ? Wl1[k*256 + c] : Wr1[k*256 + (c-256)];
            Wt1[elem] = __float2half(v);
        } else {
            int e2 = elem - 32768;
            int c = e2 >> 8, k = e2 & 255;     // Wt2[c][k], c in [0,128)
            float v = (c < 64) ? Wl2[k*64 + c] : Wr2[k*64 + (c-64)];
            Wt2[e2] = __float2half(v);
        }
        if (elem < N_GRAPHS*64) pooled[elem] = 0.f;
    } else {
        int e4 = (bk-3381)*256 + t;
        if (e4 < N_EDGES/4){
            int4 d = ((const int4*)(ei + N_EDGES))[e4];
            atomicAdd(&deg[d.x],1); atomicAdd(&deg[d.y],1);
            atomicAdd(&deg[d.z],1); atomicAdd(&deg[d.w],1);
        }
    }
}

__global__ __launch_bounds__(1024) void k_scan_a(const int* __restrict__ deg,
        int* __restrict__ rowptr, int* __restrict__ partial){
    __shared__ int s[1024];
    int t = threadIdx.x; int i = blockIdx.x*1024 + t;
    int v = (i < N_NODES) ? deg[i] : 0;
    s[t] = v; __syncthreads();
    for (int off=1; off<1024; off<<=1){
        int add = (t>=off) ? s[t-off] : 0;
        __syncthreads();
        s[t] += add;
        __syncthreads();
    }
    if (i < N_NODES) rowptr[i] = s[t] - v;
    if (t == 1023) partial[blockIdx.x] = s[1023];
}

__global__ __launch_bounds__(1024) void k_scan_c(int* __restrict__ rowptr,
        int* __restrict__ cursor, const int* __restrict__ partial){
    __shared__ int base;
    if (threadIdx.x == 0){
        int run = 0;
        for (int bk=0; bk<(int)blockIdx.x; bk++) run += partial[bk];
        base = run;
    }
    __syncthreads();
    int i = blockIdx.x*1024 + threadIdx.x;
    if (i < N_NODES){
        int r = rowptr[i] + base;
        rowptr[i] = r; cursor[i] = r;
    } else if (i == N_NODES){
        rowptr[N_NODES] = N_EDGES;
    }
}

__global__ void k_scatter(const int* __restrict__ ei, int* __restrict__ cursor,
                          int* __restrict__ srcs){
    int e4 = blockIdx.x*256 + threadIdx.x;
    if (e4 < N_EDGES/4){
        int4 sv = ((const int4*)ei)[e4];
        int4 dv = ((const int4*)(ei + N_EDGES))[e4];
        int p0 = atomicAdd(&cursor[dv.x],1); srcs[p0] = sv.x;
        int p1 = atomicAdd(&cursor[dv.y],1); srcs[p1] = sv.y;
        int p2 = atomicAdd(&cursor[dv.z],1); srcs[p2] = sv.z;
        int p3 = atomicAdd(&cursor[dv.w],1); srcs[p3] = sv.w;
    }
}

// ---- mm1: xh [N,64] fp16 @ Wt1^T (Wt1 [512 cols][64 k]) -> xl1h|xr1h [N,256] fp16
// MFMA 16x16x32 f16. Block 256 = 4 waves; wave = 16 rows x 128 cols (8 tiles x 2 K-steps).
__global__ __launch_bounds__(256) void k_mm1(const __half* __restrict__ xh,
        const __half* __restrict__ Wt1,
        __half* __restrict__ xl1h, __half* __restrict__ xr1h){
    int w = threadIdx.x >> 6, l = threadIdx.x & 63;
    int r0 = blockIdx.x*64 + w*16;
    int cg = blockIdx.y;                      // 0..3 (128 cols each; 0,1->xl 2,3->xr)
    int lr = l & 15, lk = l >> 4, lk4 = lk*4;
    int ar = r0 + lr; if (ar >= N_NODES) ar = N_NODES-1;
    const __half* arow = xh + (size_t)ar*64;
    f16x8 a0 = *(const f16x8*)(arow + lk*8);
    f16x8 a1 = *(const f16x8*)(arow + 32 + lk*8);
    f32x4 acc[8];
    #pragma unroll
    for (int ct=0; ct<8; ct++) acc[ct] = (f32x4){0.f,0.f,0.f,0.f};
    #pragma unroll
    for (int ct=0; ct<8; ct++){
        int col = cg*128 + ct*16 + lr;
        const __half* brow = Wt1 + (size_t)col*64;
        f16x8 b0 = *(const f16x8*)(brow + lk*8);
        f16x8 b1 = *(const f16x8*)(brow + 32 + lk*8);
        acc[ct] = __builtin_amdgcn_mfma_f32_16x16x32_f16(a0, b0, acc[ct], 0,0,0);
        acc[ct] = __builtin_amdgcn_mfma_f32_16x16x32_f16(a1, b1, acc[ct], 0,0,0);
    }
    __half* base = (cg < 2) ? xl1h : xr1h;
    int cbase = (cg < 2) ? cg*128 : (cg-2)*128;
    #pragma unroll
    for (int ct=0; ct<8; ct++){
        int cc = cbase + ct*16 + lr;
        #pragma unroll
        for (int i=0;i<4;i++){
            int row = r0 + lk4 + i;
            if (row < N_NODES) base[(size_t)row*256 + cc] = __float2half(acc[ct][i]);
        }
    }
}

// ---- mm2: h1h [N,256] fp16 @ Wt2^T (Wt2 [128 cols][256 k]) -> xl2h|xr2h [N,64] fp16
__global__ __launch_bounds__(256) void k_mm2(const __half* __restrict__ h1h,
        const __half* __restrict__ Wt2,
        __half* __restrict__ xl2h, __half* __restrict__ xr2h){
    int w = threadIdx.x >> 6, l = threadIdx.x & 63;
    int r0 = blockIdx.x*64 + w*16;
    int cg = blockIdx.y;                      // 0 -> xl2h, 1 -> xr2h (64 cols each)
    int lr = l & 15, lk = l >> 4, lk4 = lk*4;
    int ar = r0 + lr; if (ar >= N_NODES) ar = N_NODES-1;
    const __half* arow = h1h + (size_t)ar*256;
    f32x4 acc[4];
    #pragma unroll
    for (int ct=0; ct<4; ct++) acc[ct] = (f32x4){0.f,0.f,0.f,0.f};
    #pragma unroll
    for (int ks=0; ks<8; ks++){
        f16x8 a = *(const f16x8*)(arow + ks*32 + lk*8);
        #pragma unroll
        for (int ct=0; ct<4; ct++){
            int col = cg*64 + ct*16 + lr;
            f16x8 bf = *(const f16x8*)(Wt2 + (size_t)col*256 + ks*32 + lk*8);
            acc[ct] = __builtin_amdgcn_mfma_f32_16x16x32_f16(a, bf, acc[ct], 0,0,0);
        }
    }
    __half* base = (cg == 0) ? xl2h : xr2h;
    #pragma unroll
    for (int ct=0; ct<4; ct++){
        int cc = ct*16 + lr;
        #pragma unroll
        for (int i=0;i<4;i++){
            int row = r0 + lk4 + i;
            if (row < N_NODES) base[(size_t)row*64 + cc] = __float2half(acc[ct][i]);
        }
    }
}

// ---- fused GAT layer 1: wave per node, 4/block. 32 lanes/edge x 8 ch;
// 2 slots x 2 unroll = 4 edges in flight. pk-fp16 logit + fdot2.
__global__ __launch_bounds__(256) void k_gat1(const __half* __restrict__ xlh,
        const __half* __restrict__ xrh, const int* __restrict__ srcs,
        const int* __restrict__ rowptr, const float* __restrict__ att,
        const float* __restrict__ b, __half* __restrict__ h1h){
    int w = threadIdx.x >> 6, l = threadIdx.x & 63;
    int n = blockIdx.x*4 + w;
    int g = l >> 5, sub = l & 31;
    const float4* xh4 = (const float4*)xlh;   // 32 f4 per row
    float4 rq = *(const float4*)(xrh + (size_t)n*256 + sub*8);
    __half2 r2[4];
    { const __half2* rh = (const __half2*)&rq;
      r2[0]=rh[0]; r2[1]=rh[1]; r2[2]=rh[2]; r2[3]=rh[3]; }
    float4 A0 = *(const float4*)(att + sub*8);
    float4 A1 = *(const float4*)(att + sub*8 + 4);
    __half2 a2[4] = { __floats2half2_rn(A0.x,A0.y), __floats2half2_rn(A0.z,A0.w),
                      __floats2half2_rn(A1.x,A1.y), __floats2half2_rn(A1.z,A1.w) };
    float acc[8];
    #pragma unroll
    for (int c=0;c<8;c++) acc[c]=0.f;
    float dacc = 0.f;
    int beg = rowptr[n], end = rowptr[n+1];
    for (int j = beg; j < end; j += 8){
        int j0=j+g, j1=j+2+g, j2=j+4+g, j3=j+6+g;
        bool c0=j0<end, c1=j1<end, c2=j2<end, c3=j3<end;
        int s0 = c0 ? srcs[j0] : 0;
        int s1 = c1 ? srcs[j1] : 0;
        int s2 = c2 ? srcs[j2] : 0;
        int s3 = c3 ? srcs[j3] : 0;
        float4 q0 = xh4[(size_t)(unsigned)s0*32 + sub];
        float4 q1 = xh4[(size_t)(unsigned)s1*32 + sub];
        float4 q2 = xh4[(size_t)(unsigned)s2*32 + sub];
        float4 q3 = xh4[(size_t)(unsigned)s3*32 + sub];
        float p0 = pkdot(q0, r2, a2);
        float p1 = pkdot(q1, r2, a2);
        float p2 = pkdot(q2, r2, a2);
        float p3 = pkdot(q3, r2, a2);
        #pragma unroll
        for (int off=1; off<8; off<<=1){
            p0 += __shfl_xor(p0, off);
            p1 += __shfl_xor(p1, off);
            p2 += __shfl_xor(p2, off);
            p3 += __shfl_xor(p3, off);
        }
        float e0 = c0 ? __expf(p0) : 0.f;
        float e1 = c1 ? __expf(p1) : 0.f;
        float e2 = c2 ? __expf(p2) : 0.f;
        float e3 = c3 ? __expf(p3) : 0.f;
        float v0[8], v1[8], v2[8], v3[8];
        cvt8f(q0,v0); cvt8f(q1,v1); cvt8f(q2,v2); cvt8f(q3,v3);
        #pragma unroll
        for (int c=0;c<8;c++)
            acc[c] = fmaf(e0,v0[c], fmaf(e1,v1[c], fmaf(e2,v2[c], fmaf(e3,v3[c], acc[c]))));
        dacc += e0 + e1 + e2 + e3;
    }
    #pragma unroll
    for (int c=0;c<8;c++) acc[c] += __shfl_xor(acc[c], 32);
    dacc += __shfl_xor(dacc, 32);
    if (l < 32){
        float inv = 1.f / (dacc + 1e-16f);
        float4 B0 = *(const float4*)(b + l*8);
        float4 B1 = *(const float4*)(b + l*8 + 4);
        float4 st;
        __half2* sp = (__half2*)&st;
        sp[0] = __floats2half2_rn(elu1(fmaf(acc[0],inv,B0.x)), elu1(fmaf(acc[1],inv,B0.y)));
        sp[1] = __floats2half2_rn(elu1(fmaf(acc[2],inv,B0.z)), elu1(fmaf(acc[3],inv,B0.w)));
        sp[2] = __floats2half2_rn(elu1(fmaf(acc[4],inv,B1.x)), elu1(fmaf(acc[5],inv,B1.y)));
        sp[3] = __floats2half2_rn(elu1(fmaf(acc[6],inv,B1.z)), elu1(fmaf(acc[7],inv,B1.w)));
        *(float4*)(h1h + (size_t)n*256 + l*8) = st;
    }
}

// ---- fused GAT layer 2: wave per node; 8 lanes/edge x 8 ch;
// 8 slots x 2 unroll = 16 edges in flight. h2 out f32.
__global__ __launch_bounds__(256) void k_gat2(const __half* __restrict__ xlh,
        const __half* __restrict__ xrh, const int* __restrict__ srcs,
        const int* __restrict__ rowptr, const float* __restrict__ att,
        const float* __restrict__ b, float* __restrict__ h2){
    int w = threadIdx.x >> 6, l = threadIdx.x & 63;
    int n = blockIdx.x*4 + w;
    int g = l >> 3, sub = l & 7;
    const float4* xh4 = (const float4*)xlh;   // 8 f4 per row
    float4 rq = *(const float4*)(xrh + (size_t)n*64 + sub*8);
    __half2 r2[4];
    { const __half2* rh = (const __half2*)&rq;
      r2[0]=rh[0]; r2[1]=rh[1]; r2[2]=rh[2]; r2[3]=rh[3]; }
    float4 A0 = *(const float4*)(att + sub*8);
    float4 A1 = *(const float4*)(att + sub*8 + 4);
    __half2 a2[4] = { __floats2half2_rn(A0.x,A0.y), __floats2half2_rn(A0.z,A0.w),
                      __floats2half2_rn(A1.x,A1.y), __floats2half2_rn(A1.z,A1.w) };
    float acc[8];
    #pragma unroll
    for (int c=0;c<8;c++) acc[c]=0.f;
    float dacc = 0.f;
    int beg = rowptr[n], end = rowptr[n+1];
    for (int j = beg; j < end; j += 16){
        int j0 = j+g, j1 = j+8+g;
        bool c0 = j0<end, c1 = j1<end;
        int s0 = c0 ? srcs[j0] : 0;
        int s1 = c1 ? srcs[j1] : 0;
        float4 q0 = xh4[(size_t)(unsigned)s0*8 + sub];
        float4 q1 = xh4[(size_t)(unsigned)s1*8 + sub];
        float p0 = pkdot(q0, r2, a2);
        float p1 = pkdot(q1, r2, a2);
        #pragma unroll
        for (int off=1; off<8; off<<=1){
            p0 += __shfl_xor(p0, off);
            p1 += __shfl_xor(p1, off);
        }
        float e0 = c0 ? __expf(p0) : 0.f;
        float e1 = c1 ? __expf(p1) : 0.f;
        float v0[8], v1[8];
        cvt8f(q0,v0); cvt8f(q1,v1);
        #pragma unroll
        for (int c=0;c<8;c++)
            acc[c] = fmaf(e0,v0[c], fmaf(e1,v1[c], acc[c]));
        dacc += e0 + e1;
    }
    #pragma unroll
    for (int off=8; off<64; off<<=1){
        #pragma unroll
        for (int c=0;c<8;c++) acc[c] += __shfl_xor(acc[c], off);
        dacc += __shfl_xor(dacc, off);
    }
    if (l < 8){
        float inv = 1.f / (dacc + 1e-16f);
        float4 B0 = *(const float4*)(b + l*8);
        float4 B1 = *(const float4*)(b + l*8 + 4);
        float4 o0, o1;
        o0.x = elu1(fmaf(acc[0], inv, B0.x));
        o0.y = elu1(fmaf(acc[1], inv, B0.y));
        o0.z = elu1(fmaf(acc[2], inv, B0.z));
        o0.w = elu1(fmaf(acc[3], inv, B0.w));
        o1.x = elu1(fmaf(acc[4], inv, B1.x));
        o1.y = elu1(fmaf(acc[5], inv, B1.y));
        o1.z = elu1(fmaf(acc[6], inv, B1.z));
        o1.w = elu1(fmaf(acc[7], inv, B1.w));
        float4* op = (float4*)(h2 + (size_t)n*64 + l*8);
        op[0] = o0; op[1] = o1;
    }
}

__device__ __forceinline__ int lower_bound_i(const int* a, int n, int key){
    int lo = 0, hi = n;
    while (lo < hi){ int mid = (lo+hi)>>1; if (a[mid] < key) lo = mid+1; else hi = mid; }
    return lo;
}

// ---- mean pool: grid (64 graphs, 8 parts); atomics into pooled (zeroed in prep)
__global__ __launch_bounds__(256) void k_pool(const float* __restrict__ h2,
        const int* __restrict__ batch, float* __restrict__ pooled){
    int gph = blockIdx.x, part = blockIdx.y;
    int t = threadIdx.x, c = t & 63, q = t >> 6;
    int start = lower_bound_i(batch, N_NODES, gph);
    int end   = lower_bound_i(batch, N_NODES, gph+1);
    int len = end - start;
    int is = start + (int)(((long long)len*part) >> 3);
    int ie = start + (int)(((long long)len*(part+1)) >> 3);
    float s = 0.f;
    for (int i = is + q; i < ie; i += 4) s += h2[(size_t)i*64 + c];
    __shared__ float red[256];
    red[t] = s; __syncthreads();
    if (q == 0){
        float tot = red[c] + red[64+c] + red[128+c] + red[192+c];
        atomicAdd(&pooled[gph*64 + c], tot);
    }
}

// ---- MLP head
__global__ __launch_bounds__(64) void k_mlp(const float* __restrict__ pooled,
        const int* __restrict__ batch,
        const float* __restrict__ W3, const float* __restrict__ b3,
        const float* __restrict__ W4, const float* __restrict__ b4,
        float* __restrict__ out){
    int gph = blockIdx.x, t = threadIdx.x;
    __shared__ float ps[64], zs[64];
    int start = lower_bound_i(batch, N_NODES, gph);
    int end   = lower_bound_i(batch, N_NODES, gph+1);
    float cnt = fmaxf((float)(end - start), 1.f);
    ps[t] = pooled[gph*64 + t] / cnt;
    __syncthreads();
    float a = b3[t];
    for (int k=0;k<64;k++) a = fmaf(ps[k], W3[k*64+t], a);
    zs[t] = fmaxf(a, 0.f); __syncthreads();
    if (t < 2){
        float o = b4[t];
        for (int k=0;k<64;k++) o = fmaf(zs[k], W4[k*2+t], o);
        out[gph*2 + t] = o;
    }
}

extern "C" void kernel_launch(void* const* d_in, const int* in_sizes, int n_in,
                              void* d_out, int out_size, void* d_ws, size_t ws_size,
                              hipStream_t stream) {
    const float* x    = (const float*)d_in[0];
    const int*   ei   = (const int*)  d_in[1];   // [2, E] flat
    const int*   batch= (const int*)  d_in[2];
    const float* Wl1  = (const float*)d_in[3];
    const float* Wr1  = (const float*)d_in[4];
    const float* att1 = (const float*)d_in[5];
    const float* b1   = (const float*)d_in[6];
    const float* Wl2  = (const float*)d_in[7];
    const float* Wr2  = (const float*)d_in[8];
    const float* att2 = (const float*)d_in[9];
    const float* b2   = (const float*)d_in[10];
    const float* W3   = (const float*)d_in[11];
    const float* b3   = (const float*)d_in[12];
    const float* W4   = (const float*)d_in[13];
    const float* b4   = (const float*)d_in[14];
    float* out = (float*)d_out;

    // workspace layout
    char* wsp = (char*)d_ws;
    size_t off = 0;
    auto alloc = [&](size_t bytes) -> char* {
        char* p = wsp + off; off += (bytes + 255) & ~(size_t)255; return p;
    };
    __half* xh    = (__half*)alloc((size_t)N_NODES*64*2);     // 6.4 MB
    __half* Wt1   = (__half*)alloc(512*64*2);                 // [col][k]
    __half* Wt2   = (__half*)alloc(128*256*2);                // [col][k]
    __half* xl1h  = (__half*)alloc((size_t)N_NODES*256*2);    // 25.6 MB
    __half* xr1h  = (__half*)alloc((size_t)N_NODES*256*2);    // 25.6 MB
    __half* h1h   = (__half*)alloc((size_t)N_NODES*256*2);    // 25.6 MB
    int* rowptr   = (int*)alloc((N_NODES+1)*4);
    int* cursor   = (int*)alloc(N_NODES*4);
    int* partial  = (int*)alloc(64*4);
    int* srcs     = (int*)alloc((size_t)N_EDGES*4);
    int* deg      = (int*)alloc(N_NODES*4);
    float* pooled = (float*)alloc(N_GRAPHS*64*4);
    // overlays (dead-region reuse after k_gat1)
    __half* xl2h  = xl1h;                                     // [N,64] fp16
    __half* xr2h  = xl1h + (size_t)N_NODES*64;                // [N,64] fp16
    float*  h2    = (float*)xr1h;                             // [N,64] f32

    hipMemsetAsync(deg, 0, (size_t)N_NODES*sizeof(int), stream);
    k_prep<<<3125+256+782, 256, 0, stream>>>(x, Wl1, Wr1, Wl2, Wr2, ei,
                                             xh, Wt1, Wt2, deg, pooled);
    k_scan_a<<<49, 1024, 0, stream>>>(deg, rowptr, partial);
    k_scan_c<<<49, 1024, 0, stream>>>(rowptr, cursor, partial);
    k_scatter<<<782, 256, 0, stream>>>(ei, cursor, srcs);

    k_mm1<<<dim3(782,4), 256, 0, stream>>>(xh, Wt1, xl1h, xr1h);
    k_gat1<<<N_NODES/4, 256, 0, stream>>>(xl1h, xr1h, srcs, rowptr, att1, b1, h1h);
    k_mm2<<<dim3(782,2), 256, 0, stream>>>(h1h, Wt2, xl2h, xr2h);
    k_gat2<<<N_NODES/4, 256, 0, stream>>>(xl2h, xr2h, srcs, rowptr, att2, b2, h2);
    k_pool<<<dim3(N_GRAPHS,8), 256, 0, stream>>>(h2, batch, pooled);
    k_mlp<<<N_GRAPHS, 64, 0, stream>>>(pooled, batch, W3, b3, W4, b4, out);
}